// Round 1
// baseline (214.478 us; speedup 1.0000x reference)
//
#include <hip/hip_runtime.h>
#include <math.h>

#define NC 6
#define RM 16
#define TOPK 10
#define BSZ 32
#define G 20
#define A_TOT 8400
#define NBA (BSZ * A_TOT)

__device__ __forceinline__ void anchor_decode(int a, int& lvl, int& ai, int& w, int& hw, float& s) {
    if (a < 6400)      { lvl = 0; ai = a;        w = 80; hw = 6400; s = 8.f; }
    else if (a < 8000) { lvl = 1; ai = a - 6400; w = 40; hw = 1600; s = 16.f; }
    else               { lvl = 2; ai = a - 8000; w = 20; hw = 400;  s = 32.f; }
}

// ---------------- Kernel 1: decode boxes, logZ, transpose cls ----------------
__global__ __launch_bounds__(256) void k_prep(
        const float* __restrict__ p0, const float* __restrict__ p1, const float* __restrict__ p2,
        float* __restrict__ pd_boxes, float* __restrict__ logZ, float* __restrict__ pcls) {
    int idx = blockIdx.x * 256 + threadIdx.x;
    if (idx >= NBA) return;
    int b = idx / A_TOT, a = idx % A_TOT;
    int lvl, ai, w, hw; float s;
    anchor_decode(a, lvl, ai, w, hw, s);
    const float* p = (lvl == 0) ? p0 : ((lvl == 1) ? p1 : p2);
    const float* base = p + (size_t)b * 70 * hw + ai;   // channel stride = hw
    float ax = ((ai % w) + 0.5f) * s;
    float ay = ((ai / w) + 0.5f) * s;

    float dist[4], lz[4];
    for (int sd = 0; sd < 4; ++sd) {
        float v[RM];
        float m = -1e30f;
        #pragma unroll
        for (int k = 0; k < RM; ++k) {
            v[k] = base[(size_t)(sd * RM + k) * hw];
            m = fmaxf(m, v[k]);
        }
        float se = 0.f, sk = 0.f;
        #pragma unroll
        for (int k = 0; k < RM; ++k) {
            float e = expf(v[k] - m);
            se += e;
            sk += e * (float)k;
        }
        dist[sd] = sk / se;
        lz[sd] = m + logf(se);
    }
    float4 box;
    box.x = ax - dist[0] * s;
    box.y = ay - dist[1] * s;
    box.z = ax + dist[2] * s;
    box.w = ay + dist[3] * s;
    ((float4*)pd_boxes)[idx] = box;
    ((float4*)logZ)[idx] = make_float4(lz[0], lz[1], lz[2], lz[3]);
    #pragma unroll
    for (int c = 0; c < NC; ++c)
        pcls[(size_t)c * NBA + idx] = base[(size_t)(64 + c) * hw];
}

// ---------------- Kernel 2: align matrix, row max, top-10 mask ----------------
__global__ __launch_bounds__(256) void k_align(
        const float* __restrict__ targets,
        const float* __restrict__ pd_boxes, const float* __restrict__ pcls,
        float* __restrict__ align, float* __restrict__ amax, unsigned int* __restrict__ mask) {
    __shared__ float sa[A_TOT];
    __shared__ float rv[256];
    __shared__ int   ri[256];
    int bg = blockIdx.x;
    int b = bg / G;
    const float* t = targets + (size_t)bg * 6;
    float cx = t[2] * 640.f, cy = t[3] * 640.f;
    float hw_ = t[4] * 320.f, hh = t[5] * 320.f;
    float gx1 = cx - hw_, gy1 = cy - hh, gx2 = cx + hw_, gy2 = cy + hh;
    int lab = (int)t[1];
    int g = bg % G;
    const float* pc = pcls + (size_t)lab * NBA + (size_t)b * A_TOT;
    const float4* pb = (const float4*)pd_boxes + (size_t)b * A_TOT;
    float* arow = align + (size_t)bg * A_TOT;
    const float eps = 1e-7f;
    float gw = fmaxf(gx2 - gx1, eps), gh = fmaxf(gy2 - gy1, eps);
    float garea = gw * gh;

    for (int a = threadIdx.x; a < A_TOT; a += 256) {
        float4 box = pb[a];
        float x1 = fmaxf(gx1, box.x), y1 = fmaxf(gy1, box.y);
        float x2 = fminf(gx2, box.z), y2 = fminf(gy2, box.w);
        float inter = fmaxf(x2 - x1, 0.f) * fmaxf(y2 - y1, 0.f);
        float w2 = fmaxf(box.z - box.x, eps), h2 = fmaxf(box.w - box.y, eps);
        float uni = garea + w2 * h2 - inter + eps;
        float iou = inter / uni;
        float sc = 1.f / (1.f + expf(-pc[a]));
        int lvl, ai, w_, hwc; float s;
        anchor_decode(a, lvl, ai, w_, hwc, s);
        float ax = ((ai % w_) + 0.5f) * s, ay = ((ai / w_) + 0.5f) * s;
        float mn = fminf(fminf(ax - gx1, ay - gy1), fminf(gx2 - ax, gy2 - ay));
        float al = 0.f;
        if (mn > 1e-9f) {
            float i2 = iou * iou;
            al = sqrtf(sc) * (i2 * i2 * i2);
        }
        sa[a] = al;
        arow[a] = al;
    }
    __syncthreads();

    for (int it = 0; it < TOPK; ++it) {
        float v = -1.f; int vi = -1;
        for (int a = threadIdx.x; a < A_TOT; a += 256) {
            float x = sa[a];
            if (x > v) { v = x; vi = a; }   // strict > keeps lowest index per thread
        }
        rv[threadIdx.x] = v; ri[threadIdx.x] = vi;
        __syncthreads();
        for (int off = 128; off > 0; off >>= 1) {
            if (threadIdx.x < off) {
                float ov = rv[threadIdx.x + off]; int oi = ri[threadIdx.x + off];
                if (ov > rv[threadIdx.x] ||
                    (ov == rv[threadIdx.x] && oi >= 0 &&
                     (ri[threadIdx.x] < 0 || oi < ri[threadIdx.x]))) {
                    rv[threadIdx.x] = ov; ri[threadIdx.x] = oi;
                }
            }
            __syncthreads();
        }
        if (threadIdx.x == 0) {
            float v0 = rv[0]; int i0 = ri[0];
            if (it == 0) amax[bg] = fmaxf(v0, 0.f);
            if (i0 >= 0) {
                if (v0 > 0.f) atomicOr(&mask[(size_t)b * A_TOT + i0], 1u << g);
                sa[i0] = -2.f;
            }
        }
        __syncthreads();
    }
}

// ---------------- Kernel 3: per-anchor losses ----------------
__global__ __launch_bounds__(256) void k_loss(
        const float* __restrict__ targets,
        const float* __restrict__ pd_boxes, const float* __restrict__ logZ,
        const float* __restrict__ pcls, const float* __restrict__ align,
        const float* __restrict__ amax, const unsigned int* __restrict__ mask,
        const float* __restrict__ p0, const float* __restrict__ p1, const float* __restrict__ p2,
        double* __restrict__ accum) {
    int idx = blockIdx.x * 256 + threadIdx.x;
    float bce_s = 0.f, bbox_s = 0.f, dfl_s = 0.f, fg_s = 0.f;
    if (idx < NBA) {
        int b = idx / A_TOT, a = idx % A_TOT;
        unsigned int m = mask[idx];
        if (__popc(m) > 1) {
            float best = -1.f; int bg_ = 0;
            for (int g = 0; g < G; ++g) {
                float x = align[((size_t)b * G + g) * A_TOT + a];
                if (x > best) { best = x; bg_ = g; }
            }
            m = 1u << bg_;
        }
        bool fg = (m != 0u);
        float4 box = ((const float4*)pd_boxes)[idx];
        float tbx1 = 0.f, tby1 = 0.f, tbx2 = 0.f, tby2 = 0.f;
        float sval = 0.f; int lab = -1;
        const float eps = 1e-7f;
        if (fg) {
            int gidx = __ffs(m) - 1;
            const float* t = targets + ((size_t)b * G + gidx) * 6;
            lab = (int)t[1];
            float cx = t[2] * 640.f, cy = t[3] * 640.f;
            float hw_ = t[4] * 320.f, hh = t[5] * 320.f;
            tbx1 = cx - hw_; tby1 = cy - hh; tbx2 = cx + hw_; tby2 = cy + hh;
            float x1 = fmaxf(box.x, tbx1), y1 = fmaxf(box.y, tby1);
            float x2 = fminf(box.z, tbx2), y2 = fminf(box.w, tby2);
            float inter = fmaxf(x2 - x1, 0.f) * fmaxf(y2 - y1, 0.f);
            float w1 = fmaxf(box.z - box.x, eps), h1 = fmaxf(box.w - box.y, eps);
            float w2 = fmaxf(tbx2 - tbx1, eps), h2 = fmaxf(tby2 - tby1, eps);
            float uni = w1 * h1 + w2 * h2 - inter + eps;
            float iou_fg = fmaxf(inter / uni, 0.f);
            float al = align[((size_t)b * G + gidx) * A_TOT + a];
            sval = (al / (amax[b * G + gidx] + 1e-9f)) * iou_fg;
            fg_s = 1.f;
        }
        #pragma unroll
        for (int c = 0; c < NC; ++c) {
            float x = pcls[(size_t)c * NBA + idx];
            float ts = (fg && c == lab) ? sval : 0.f;
            bce_s += fmaxf(x, 0.f) - x * ts + log1pf(expf(-fabsf(x)));
        }
        if (fg) {
            // CIoU(pred, target)
            float x1 = fmaxf(box.x, tbx1), y1 = fmaxf(box.y, tby1);
            float x2 = fminf(box.z, tbx2), y2 = fminf(box.w, tby2);
            float inter = fmaxf(x2 - x1, 0.f) * fmaxf(y2 - y1, 0.f);
            float w1 = fmaxf(box.z - box.x, eps), h1 = fmaxf(box.w - box.y, eps);
            float w2 = fmaxf(tbx2 - tbx1, eps), h2 = fmaxf(tby2 - tby1, eps);
            float uni = w1 * h1 + w2 * h2 - inter + eps;
            float iou = inter / uni;
            float cw = fmaxf(box.z, tbx2) - fminf(box.x, tbx1);
            float ch = fmaxf(box.w, tby2) - fminf(box.y, tby1);
            float c2 = cw * cw + ch * ch + eps;
            float dx = box.x + box.z - tbx1 - tbx2;
            float dy = box.y + box.w - tby1 - tby2;
            float rho2 = (dx * dx + dy * dy) * 0.25f;
            float dv = atanf(w2 / h2) - atanf(w1 / h1);
            float v = 0.40528473f * dv * dv;            // 4/pi^2
            float alpha = v / (v - iou + (1.f + eps));
            float ciou = iou - (rho2 / c2 + v * alpha);
            bbox_s = 1.f - ciou;
            // DFL
            int lvl, ai, w_, hwc; float s;
            anchor_decode(a, lvl, ai, w_, hwc, s);
            float ax = ((ai % w_) + 0.5f) * s, ay = ((ai / w_) + 0.5f) * s;
            const float* p = (lvl == 0) ? p0 : ((lvl == 1) ? p1 : p2);
            const float* base = p + (size_t)b * 70 * hwc + ai;
            float4 lzv = ((const float4*)logZ)[idx];
            float lz[4] = {lzv.x, lzv.y, lzv.z, lzv.w};
            float lt[4] = {(ax - tbx1) / s, (ay - tby1) / s, (tbx2 - ax) / s, (tby2 - ay) / s};
            #pragma unroll
            for (int sd = 0; sd < 4; ++sd) {
                float d = fminf(fmaxf(lt[sd], 0.f), (float)RM - 1.01f);
                int tl = (int)d;
                float wl = (float)(tl + 1) - d;
                float wr = d - (float)tl;
                float xl = base[(size_t)(sd * RM + tl) * hwc];
                float xr = base[(size_t)(sd * RM + tl + 1) * hwc];
                dfl_s += (lz[sd] - xl) * wl + (lz[sd] - xr) * wr;
            }
        }
    }
    // block reduce 4 quantities: wave shuffle then cross-wave LDS
    __shared__ float part[4][4];
    int lane = threadIdx.x & 63, wv = threadIdx.x >> 6;
    #pragma unroll
    for (int off = 32; off > 0; off >>= 1) {
        bce_s  += __shfl_down(bce_s,  off);
        bbox_s += __shfl_down(bbox_s, off);
        dfl_s  += __shfl_down(dfl_s,  off);
        fg_s   += __shfl_down(fg_s,   off);
    }
    if (lane == 0) {
        part[wv][0] = bce_s; part[wv][1] = bbox_s;
        part[wv][2] = dfl_s; part[wv][3] = fg_s;
    }
    __syncthreads();
    if (threadIdx.x == 0) {
        float s0 = 0.f, s1 = 0.f, s2 = 0.f, s3 = 0.f;
        for (int i = 0; i < 4; ++i) {
            s0 += part[i][0]; s1 += part[i][1]; s2 += part[i][2]; s3 += part[i][3];
        }
        atomicAdd(&accum[0], (double)s0);
        atomicAdd(&accum[1], (double)s1);
        atomicAdd(&accum[2], (double)s2);
        atomicAdd(&accum[3], (double)s3);
    }
}

// ---------------- Kernel 4: combine ----------------
__global__ void k_final(const double* __restrict__ accum, float* __restrict__ out) {
    if (threadIdx.x == 0 && blockIdx.x == 0) {
        double bce = accum[0], bbox = accum[1], dfl = accum[2], fgc = accum[3];
        double l_cls = bce / (double)A_TOT;
        double np_ = fmax(fgc, 1.0);
        double l_bbox = 7.5 * bbox / np_;
        double l_dfl = 1.5 * dfl / np_;
        out[0] = (float)(l_cls + l_bbox + l_dfl);
        out[1] = (float)l_cls;
        out[2] = (float)l_bbox;
        out[3] = 0.f;
        out[4] = (float)l_dfl;
    }
}

extern "C" void kernel_launch(void* const* d_in, const int* in_sizes, int n_in,
                              void* d_out, int out_size, void* d_ws, size_t ws_size,
                              hipStream_t stream) {
    const float* p0 = (const float*)d_in[0];
    const float* p1 = (const float*)d_in[1];
    const float* p2 = (const float*)d_in[2];
    const float* targets = (const float*)d_in[3];
    float* out = (float*)d_out;

    char* ws = (char*)d_ws;
    size_t off = 0;
    float* pd_boxes = (float*)(ws + off); off += (size_t)NBA * 4 * sizeof(float);
    float* logZ     = (float*)(ws + off); off += (size_t)NBA * 4 * sizeof(float);
    float* pcls     = (float*)(ws + off); off += (size_t)NC * NBA * sizeof(float);
    float* align    = (float*)(ws + off); off += (size_t)BSZ * G * A_TOT * sizeof(float);
    float* amax     = (float*)(ws + off); off += (size_t)BSZ * G * sizeof(float);
    unsigned int* mask = (unsigned int*)(ws + off); off += (size_t)NBA * sizeof(unsigned int);
    off = (off + 15) & ~(size_t)15;
    double* accum   = (double*)(ws + off); off += 4 * sizeof(double);

    hipMemsetAsync(mask, 0, (size_t)NBA * sizeof(unsigned int), stream);
    hipMemsetAsync(accum, 0, 4 * sizeof(double), stream);

    k_prep<<<(NBA + 255) / 256, 256, 0, stream>>>(p0, p1, p2, pd_boxes, logZ, pcls);
    k_align<<<BSZ * G, 256, 0, stream>>>(targets, pd_boxes, pcls, align, amax, mask);
    k_loss<<<(NBA + 255) / 256, 256, 0, stream>>>(targets, pd_boxes, logZ, pcls, align,
                                                  amax, mask, p0, p1, p2, accum);
    k_final<<<1, 64, 0, stream>>>(accum, out);
}

// Round 2
// 151.575 us; speedup vs baseline: 1.4150x; 1.4150x over previous
//
#include <hip/hip_runtime.h>
#include <math.h>

#define NC 6
#define RM 16
#define TOPK 10
#define BSZ 32
#define G 20
#define A_TOT 8400
#define NBA (BSZ * A_TOT)
#define NBLK_LOSS ((NBA + 255) / 256)
#define MAXCAND 1024

__device__ __forceinline__ void anchor_decode(int a, int& lvl, int& ai, int& w, int& hw, float& s) {
    if (a < 6400)      { lvl = 0; ai = a;        w = 80; hw = 6400; s = 8.f; }
    else if (a < 8000) { lvl = 1; ai = a - 6400; w = 40; hw = 1600; s = 16.f; }
    else               { lvl = 2; ai = a - 8000; w = 20; hw = 400;  s = 32.f; }
}

// ---------------- Kernel 1: decode boxes, logZ, transpose cls ----------------
__global__ __launch_bounds__(256) void k_prep(
        const float* __restrict__ p0, const float* __restrict__ p1, const float* __restrict__ p2,
        float* __restrict__ pd_boxes, float* __restrict__ logZ, float* __restrict__ pcls) {
    int idx = blockIdx.x * 256 + threadIdx.x;
    if (idx >= NBA) return;
    int b = idx / A_TOT, a = idx % A_TOT;
    int lvl, ai, w, hw; float s;
    anchor_decode(a, lvl, ai, w, hw, s);
    const float* p = (lvl == 0) ? p0 : ((lvl == 1) ? p1 : p2);
    const float* base = p + (size_t)b * 70 * hw + ai;   // channel stride = hw
    float ax = ((ai % w) + 0.5f) * s;
    float ay = ((ai / w) + 0.5f) * s;

    float dist[4], lz[4];
    for (int sd = 0; sd < 4; ++sd) {
        float v[RM];
        float m = -1e30f;
        #pragma unroll
        for (int k = 0; k < RM; ++k) {
            v[k] = base[(size_t)(sd * RM + k) * hw];
            m = fmaxf(m, v[k]);
        }
        float se = 0.f, sk = 0.f;
        #pragma unroll
        for (int k = 0; k < RM; ++k) {
            float e = expf(v[k] - m);
            se += e;
            sk += e * (float)k;
        }
        dist[sd] = sk / se;
        lz[sd] = m + logf(se);
    }
    float4 box;
    box.x = ax - dist[0] * s;
    box.y = ay - dist[1] * s;
    box.z = ax + dist[2] * s;
    box.w = ay + dist[3] * s;
    ((float4*)pd_boxes)[idx] = box;
    ((float4*)logZ)[idx] = make_float4(lz[0], lz[1], lz[2], lz[3]);
    #pragma unroll
    for (int c = 0; c < NC; ++c)
        pcls[(size_t)c * NBA + idx] = base[(size_t)(64 + c) * hw];
}

// prefer higher value; on tie prefer LOWER index (matches jax.lax.top_k)
__device__ __forceinline__ bool cand_better(float av, int ai_, float bv, int bi_) {
    if (av > bv) return true;
    if (av < bv) return false;
    if (ai_ < 0) return false;
    if (bi_ < 0) return true;
    return ai_ < bi_;
}

// ---------------- Kernel 2: align matrix, row max, top-10 mask ----------------
__global__ __launch_bounds__(256) void k_align(
        const float* __restrict__ targets,
        const float* __restrict__ pd_boxes, const float* __restrict__ pcls,
        float* __restrict__ align, float* __restrict__ amax, unsigned int* __restrict__ mask) {
    __shared__ float cval[MAXCAND];
    __shared__ int   cidx[MAXCAND];
    __shared__ int   cnt_s;
    __shared__ float rv[4];
    __shared__ int   ri[4];
    __shared__ float win_v_s;
    __shared__ int   win_i_s;

    int bg = blockIdx.x;
    int b = bg / G;
    int g = bg % G;
    const float* t = targets + (size_t)bg * 6;
    float cx = t[2] * 640.f, cy = t[3] * 640.f;
    float hw_ = t[4] * 320.f, hh = t[5] * 320.f;
    float gx1 = cx - hw_, gy1 = cy - hh, gx2 = cx + hw_, gy2 = cy + hh;
    int lab = (int)t[1];
    const float* pc = pcls + (size_t)lab * NBA + (size_t)b * A_TOT;
    const float4* pb = (const float4*)pd_boxes + (size_t)b * A_TOT;
    float* arow = align + (size_t)bg * A_TOT;
    const float eps = 1e-7f;
    float gw = fmaxf(gx2 - gx1, eps), gh = fmaxf(gy2 - gy1, eps);
    float garea = gw * gh;

    if (threadIdx.x == 0) cnt_s = 0;
    __syncthreads();

    for (int a = threadIdx.x; a < A_TOT; a += 256) {
        float4 box = pb[a];
        float x1 = fmaxf(gx1, box.x), y1 = fmaxf(gy1, box.y);
        float x2 = fminf(gx2, box.z), y2 = fminf(gy2, box.w);
        float inter = fmaxf(x2 - x1, 0.f) * fmaxf(y2 - y1, 0.f);
        float w2 = fmaxf(box.z - box.x, eps), h2 = fmaxf(box.w - box.y, eps);
        float uni = garea + w2 * h2 - inter + eps;
        float iou = inter / uni;
        float sc = 1.f / (1.f + expf(-pc[a]));
        int lvl, ai, w_, hwc; float s;
        anchor_decode(a, lvl, ai, w_, hwc, s);
        float ax = ((ai % w_) + 0.5f) * s, ay = ((ai / w_) + 0.5f) * s;
        float mn = fminf(fminf(ax - gx1, ay - gy1), fminf(gx2 - ax, gy2 - ay));
        float al = 0.f;
        if (mn > 1e-9f) {
            float i2 = iou * iou;
            al = sqrtf(sc) * (i2 * i2 * i2);
        }
        arow[a] = al;
        if (al > 0.f) {
            int p = atomicAdd(&cnt_s, 1);
            if (p < MAXCAND) { cval[p] = al; cidx[p] = a; }
        }
    }
    __syncthreads();
    int cnt = min(cnt_s, MAXCAND);

    // candidates into registers
    float mv[MAXCAND / 256];
    int   mi[MAXCAND / 256];
    #pragma unroll
    for (int r = 0; r < MAXCAND / 256; ++r) {
        int p = threadIdx.x + r * 256;
        mv[r] = (p < cnt) ? cval[p] : -1.f;
        mi[r] = (p < cnt) ? cidx[p] : -1;
    }

    int lane = threadIdx.x & 63, wv = threadIdx.x >> 6;
    for (int it = 0; it < TOPK; ++it) {
        float v = -1.f; int vi = -1;
        #pragma unroll
        for (int r = 0; r < MAXCAND / 256; ++r)
            if (cand_better(mv[r], mi[r], v, vi)) { v = mv[r]; vi = mi[r]; }
        #pragma unroll
        for (int off = 32; off > 0; off >>= 1) {
            float ov = __shfl_down(v, off);
            int   oi = __shfl_down(vi, off);
            if (cand_better(ov, oi, v, vi)) { v = ov; vi = oi; }
        }
        if (lane == 0) { rv[wv] = v; ri[wv] = vi; }
        __syncthreads();
        if (threadIdx.x == 0) {
            float v0 = rv[0]; int i0 = ri[0];
            for (int i = 1; i < 4; ++i)
                if (cand_better(rv[i], ri[i], v0, i0)) { v0 = rv[i]; i0 = ri[i]; }
            if (it == 0) amax[bg] = fmaxf(v0, 0.f);
            if (i0 >= 0 && v0 > 0.f) atomicOr(&mask[(size_t)b * A_TOT + i0], 1u << g);
            win_v_s = v0; win_i_s = i0;
        }
        __syncthreads();
        int wi = win_i_s;
        if (wi < 0) break;                 // uniform: no candidates left
        #pragma unroll
        for (int r = 0; r < MAXCAND / 256; ++r)
            if (mi[r] == wi) { mv[r] = -1.f; mi[r] = -1; }
    }
}

// ---------------- Kernel 3: per-anchor losses, per-block partials ----------------
__global__ __launch_bounds__(256) void k_loss(
        const float* __restrict__ targets,
        const float* __restrict__ pd_boxes, const float* __restrict__ logZ,
        const float* __restrict__ pcls, const float* __restrict__ align,
        const float* __restrict__ amax, const unsigned int* __restrict__ mask,
        const float* __restrict__ p0, const float* __restrict__ p1, const float* __restrict__ p2,
        float* __restrict__ partial) {
    int idx = blockIdx.x * 256 + threadIdx.x;
    float bce_s = 0.f, bbox_s = 0.f, dfl_s = 0.f, fg_s = 0.f;
    if (idx < NBA) {
        int b = idx / A_TOT, a = idx % A_TOT;
        unsigned int m = mask[idx];
        if (__popc(m) > 1) {
            float best = -1.f; int bg_ = 0;
            for (int g = 0; g < G; ++g) {
                float x = align[((size_t)b * G + g) * A_TOT + a];
                if (x > best) { best = x; bg_ = g; }
            }
            m = 1u << bg_;
        }
        bool fg = (m != 0u);
        float4 box = ((const float4*)pd_boxes)[idx];
        float tbx1 = 0.f, tby1 = 0.f, tbx2 = 0.f, tby2 = 0.f;
        float sval = 0.f; int lab = -1;
        const float eps = 1e-7f;
        if (fg) {
            int gidx = __ffs(m) - 1;
            const float* t = targets + ((size_t)b * G + gidx) * 6;
            lab = (int)t[1];
            float cx = t[2] * 640.f, cy = t[3] * 640.f;
            float hw_ = t[4] * 320.f, hh = t[5] * 320.f;
            tbx1 = cx - hw_; tby1 = cy - hh; tbx2 = cx + hw_; tby2 = cy + hh;
            float x1 = fmaxf(box.x, tbx1), y1 = fmaxf(box.y, tby1);
            float x2 = fminf(box.z, tbx2), y2 = fminf(box.w, tby2);
            float inter = fmaxf(x2 - x1, 0.f) * fmaxf(y2 - y1, 0.f);
            float w1 = fmaxf(box.z - box.x, eps), h1 = fmaxf(box.w - box.y, eps);
            float w2 = fmaxf(tbx2 - tbx1, eps), h2 = fmaxf(tby2 - tby1, eps);
            float uni = w1 * h1 + w2 * h2 - inter + eps;
            float iou_fg = fmaxf(inter / uni, 0.f);
            float al = align[((size_t)b * G + gidx) * A_TOT + a];
            sval = (al / (amax[b * G + gidx] + 1e-9f)) * iou_fg;
            fg_s = 1.f;
        }
        #pragma unroll
        for (int c = 0; c < NC; ++c) {
            float x = pcls[(size_t)c * NBA + idx];
            float ts = (fg && c == lab) ? sval : 0.f;
            bce_s += fmaxf(x, 0.f) - x * ts + log1pf(expf(-fabsf(x)));
        }
        if (fg) {
            // CIoU(pred, target)
            float x1 = fmaxf(box.x, tbx1), y1 = fmaxf(box.y, tby1);
            float x2 = fminf(box.z, tbx2), y2 = fminf(box.w, tby2);
            float inter = fmaxf(x2 - x1, 0.f) * fmaxf(y2 - y1, 0.f);
            float w1 = fmaxf(box.z - box.x, eps), h1 = fmaxf(box.w - box.y, eps);
            float w2 = fmaxf(tbx2 - tbx1, eps), h2 = fmaxf(tby2 - tby1, eps);
            float uni = w1 * h1 + w2 * h2 - inter + eps;
            float iou = inter / uni;
            float cw = fmaxf(box.z, tbx2) - fminf(box.x, tbx1);
            float ch = fmaxf(box.w, tby2) - fminf(box.y, tby1);
            float c2 = cw * cw + ch * ch + eps;
            float dx = box.x + box.z - tbx1 - tbx2;
            float dy = box.y + box.w - tby1 - tby2;
            float rho2 = (dx * dx + dy * dy) * 0.25f;
            float dv = atanf(w2 / h2) - atanf(w1 / h1);
            float v = 0.40528473f * dv * dv;            // 4/pi^2
            float alpha = v / (v - iou + (1.f + eps));
            float ciou = iou - (rho2 / c2 + v * alpha);
            bbox_s = 1.f - ciou;
            // DFL
            int lvl, ai, w_, hwc; float s;
            anchor_decode(a, lvl, ai, w_, hwc, s);
            float ax = ((ai % w_) + 0.5f) * s, ay = ((ai / w_) + 0.5f) * s;
            const float* p = (lvl == 0) ? p0 : ((lvl == 1) ? p1 : p2);
            const float* base = p + (size_t)b * 70 * hwc + ai;
            float4 lzv = ((const float4*)logZ)[idx];
            float lz[4] = {lzv.x, lzv.y, lzv.z, lzv.w};
            float lt[4] = {(ax - tbx1) / s, (ay - tby1) / s, (tbx2 - ax) / s, (tby2 - ay) / s};
            #pragma unroll
            for (int sd = 0; sd < 4; ++sd) {
                float d = fminf(fmaxf(lt[sd], 0.f), (float)RM - 1.01f);
                int tl = (int)d;
                float wl = (float)(tl + 1) - d;
                float wr = d - (float)tl;
                float xl = base[(size_t)(sd * RM + tl) * hwc];
                float xr = base[(size_t)(sd * RM + tl + 1) * hwc];
                dfl_s += (lz[sd] - xl) * wl + (lz[sd] - xr) * wr;
            }
        }
    }
    // block reduce 4 quantities: wave shuffle then cross-wave LDS
    __shared__ float part[4][4];
    int lane = threadIdx.x & 63, wv = threadIdx.x >> 6;
    #pragma unroll
    for (int off = 32; off > 0; off >>= 1) {
        bce_s  += __shfl_down(bce_s,  off);
        bbox_s += __shfl_down(bbox_s, off);
        dfl_s  += __shfl_down(dfl_s,  off);
        fg_s   += __shfl_down(fg_s,   off);
    }
    if (lane == 0) {
        part[wv][0] = bce_s; part[wv][1] = bbox_s;
        part[wv][2] = dfl_s; part[wv][3] = fg_s;
    }
    __syncthreads();
    if (threadIdx.x == 0) {
        float s0 = 0.f, s1 = 0.f, s2 = 0.f, s3 = 0.f;
        for (int i = 0; i < 4; ++i) {
            s0 += part[i][0]; s1 += part[i][1]; s2 += part[i][2]; s3 += part[i][3];
        }
        float4* pp = (float4*)partial;
        pp[blockIdx.x] = make_float4(s0, s1, s2, s3);
    }
}

// ---------------- Kernel 4: reduce partials, combine ----------------
__global__ __launch_bounds__(256) void k_final(const float* __restrict__ partial,
                                               float* __restrict__ out) {
    double s0 = 0., s1 = 0., s2 = 0., s3 = 0.;
    for (int i = threadIdx.x; i < NBLK_LOSS; i += 256) {
        float4 p = ((const float4*)partial)[i];
        s0 += p.x; s1 += p.y; s2 += p.z; s3 += p.w;
    }
    #pragma unroll
    for (int off = 32; off > 0; off >>= 1) {
        s0 += __shfl_down(s0, off);
        s1 += __shfl_down(s1, off);
        s2 += __shfl_down(s2, off);
        s3 += __shfl_down(s3, off);
    }
    __shared__ double part[4][4];
    int lane = threadIdx.x & 63, wv = threadIdx.x >> 6;
    if (lane == 0) { part[wv][0] = s0; part[wv][1] = s1; part[wv][2] = s2; part[wv][3] = s3; }
    __syncthreads();
    if (threadIdx.x == 0) {
        double bce = 0., bbox = 0., dfl = 0., fgc = 0.;
        for (int i = 0; i < 4; ++i) {
            bce += part[i][0]; bbox += part[i][1]; dfl += part[i][2]; fgc += part[i][3];
        }
        double l_cls = bce / (double)A_TOT;
        double np_ = fmax(fgc, 1.0);
        double l_bbox = 7.5 * bbox / np_;
        double l_dfl = 1.5 * dfl / np_;
        out[0] = (float)(l_cls + l_bbox + l_dfl);
        out[1] = (float)l_cls;
        out[2] = (float)l_bbox;
        out[3] = 0.f;
        out[4] = (float)l_dfl;
    }
}

extern "C" void kernel_launch(void* const* d_in, const int* in_sizes, int n_in,
                              void* d_out, int out_size, void* d_ws, size_t ws_size,
                              hipStream_t stream) {
    const float* p0 = (const float*)d_in[0];
    const float* p1 = (const float*)d_in[1];
    const float* p2 = (const float*)d_in[2];
    const float* targets = (const float*)d_in[3];
    float* out = (float*)d_out;

    char* ws = (char*)d_ws;
    size_t off = 0;
    float* pd_boxes = (float*)(ws + off); off += (size_t)NBA * 4 * sizeof(float);
    float* logZ     = (float*)(ws + off); off += (size_t)NBA * 4 * sizeof(float);
    float* pcls     = (float*)(ws + off); off += (size_t)NC * NBA * sizeof(float);
    float* align    = (float*)(ws + off); off += (size_t)BSZ * G * A_TOT * sizeof(float);
    float* amax     = (float*)(ws + off); off += (size_t)BSZ * G * sizeof(float);
    unsigned int* mask = (unsigned int*)(ws + off); off += (size_t)NBA * sizeof(unsigned int);
    float* partial  = (float*)(ws + off); off += (size_t)NBLK_LOSS * 4 * sizeof(float);

    hipMemsetAsync(mask, 0, (size_t)NBA * sizeof(unsigned int), stream);

    k_prep<<<(NBA + 255) / 256, 256, 0, stream>>>(p0, p1, p2, pd_boxes, logZ, pcls);
    k_align<<<BSZ * G, 256, 0, stream>>>(targets, pd_boxes, pcls, align, amax, mask);
    k_loss<<<NBLK_LOSS, 256, 0, stream>>>(targets, pd_boxes, logZ, pcls, align,
                                          amax, mask, p0, p1, p2, partial);
    k_final<<<1, 256, 0, stream>>>(partial, out);
}